// Round 1
// baseline (669.494 us; speedup 1.0000x reference)
//
#include <hip/hip_runtime.h>
#include <hip/hip_fp16.h>

constexpr int NN  = 50000;   // nodes
constexpr int NE  = 800000;  // edges
constexpr int CIN = 128;     // input channels
constexpr int CH  = 256;     // hidden channels
constexpr int NG  = 512;     // graphs

typedef unsigned short ushort_t;
typedef unsigned int uint_t;

static __device__ __forceinline__ ushort_t f2bf(float f) {
    uint_t u = __float_as_uint(f);
    u += 0x7fffu + ((u >> 16) & 1u);   // round-to-nearest-even
    return (ushort_t)(u >> 16);
}

static __device__ __forceinline__ float h16tof(uint_t bits) {
    return __half2float(__ushort_as_half((unsigned short)bits));
}

// ================= prep: fp32 -> bf16 converts =================
__global__ void conv_x_kernel(const float4* __restrict__ x, ushort4* __restrict__ xb, int n4) {
    int i = blockIdx.x * blockDim.x + threadIdx.x;
    if (i >= n4) return;
    float4 v = x[i];
    ushort4 o;
    o.x = f2bf(v.x); o.y = f2bf(v.y); o.z = f2bf(v.z); o.w = f2bf(v.w);
    xb[i] = o;
}

// Wt[n*K + k] = bf16(W[k*N + n])
__global__ void conv_wt_kernel(const float* __restrict__ W, ushort_t* __restrict__ Wt, int K, int N) {
    int i = blockIdx.x * blockDim.x + threadIdx.x;
    if (i >= K * N) return;
    int k = i / N, n = i % N;
    Wt[(size_t)n * K + k] = f2bf(W[i]);
}

// ================= CSR build =================
__global__ void count_kernel(const int* __restrict__ dst, int* __restrict__ cnt, int E) {
    int e = blockIdx.x * blockDim.x + threadIdx.x;
    if (e < E) atomicAdd(&cnt[dst[e]], 1);
}

__global__ __launch_bounds__(256) void scan_bsum_kernel(const int* __restrict__ cnt,
                                                        int* __restrict__ bsum, int n) {
    int i = blockIdx.x * 256 + threadIdx.x;
    int v = (i < n) ? cnt[i] : 0;
    #pragma unroll
    for (int off = 32; off >= 1; off >>= 1) v += __shfl_xor(v, off, 64);
    __shared__ int ws[4];
    if ((threadIdx.x & 63) == 0) ws[threadIdx.x >> 6] = v;
    __syncthreads();
    if (threadIdx.x == 0) bsum[blockIdx.x] = ws[0] + ws[1] + ws[2] + ws[3];
}

__global__ __launch_bounds__(256) void scan_boff_kernel(int* __restrict__ bsum, int nb) {
    int tid = threadIdx.x, lane = tid & 63, wid = tid >> 6;
    int v = (tid < nb) ? bsum[tid] : 0;
    int s = v;
    #pragma unroll
    for (int off = 1; off < 64; off <<= 1) {
        int t = __shfl_up(s, off, 64);
        if (lane >= off) s += t;
    }
    __shared__ int wsum[4];
    if (lane == 63) wsum[wid] = s;
    __syncthreads();
    int wadd = 0;
    #pragma unroll
    for (int w = 0; w < 4; w++) if (w < wid) wadd += wsum[w];
    if (tid < nb) bsum[tid] = wadd + s - v;   // exclusive
}

__global__ __launch_bounds__(256) void scan_final_kernel(const int* __restrict__ cnt,
                                                         const int* __restrict__ boff,
                                                         int* __restrict__ rowptr,
                                                         float* __restrict__ dinv, int n) {
    int tid = threadIdx.x, lane = tid & 63, wid = tid >> 6;
    int i = blockIdx.x * 256 + tid;
    int v = (i < n) ? cnt[i] : 0;
    int s = v;
    #pragma unroll
    for (int off = 1; off < 64; off <<= 1) {
        int t = __shfl_up(s, off, 64);
        if (lane >= off) s += t;
    }
    __shared__ int wsum[4];
    if (lane == 63) wsum[wid] = s;
    __syncthreads();
    int wadd = boff[blockIdx.x];
    #pragma unroll
    for (int w = 0; w < 4; w++) if (w < wid) wadd += wsum[w];
    if (i < n) {
        rowptr[i] = wadd + s - v;
        dinv[i]   = rsqrtf((float)v + 1.0f);   // +1 self loop
        if (i == n - 1) rowptr[n] = wadd + s;
    }
}

// scatter: write packed {src:16, f16(dinv[src]):16} per CSR slot (4 B/edge).
// NN = 50000 < 65536 so src fits in 16 bits.
__global__ void scatter_kernel(const int* __restrict__ src, const int* __restrict__ dst,
                               const int* __restrict__ rowptr, int* __restrict__ cursor,
                               const float* __restrict__ dinv, uint_t* __restrict__ epack, int E) {
    int e = blockIdx.x * blockDim.x + threadIdx.x;
    if (e >= E) return;
    int d = dst[e];
    int s = src[e];
    int p = rowptr[d] + atomicAdd(&cursor[d], 1);
    uint_t hb = (uint_t)__half_as_ushort(__float2half(dinv[s]));
    epack[p] = (uint_t)s | (hb << 16);
}

// ============ XCD-sliced per-node gather aggregation (bf16) ============
// Channel-slice partitioning: blockIdx.x = slice s (0..7) handles channels
// [s*C/8, (s+1)*C/8). gridDim.x = 8 so linear block id = x + 8*y -> XCD = x
// under round-robin dispatch. Per-XCD gather working set = NN * (C/8) * 2 B
// = 3.2 MB (C=256) / 1.6 MB (C=128) -> fits 4 MiB per-XCD L2; gathers become
// L2 hits instead of L3/fabric misses (old FETCH 187 MB = per-XCD compulsory
// re-stream of h).
// Wave layout: NPG nodes per wave, one lane-group (GL lanes) per node, lane
// owns 2 channels (1 dword of the row). One edge per group per step, 8 steps
// unrolled -> 8 epack loads + 8 gathers in flight per wave.
// MODE 0: out(bf16) = dd*sum + dd^2*self
// MODE 1: out(bf16) = relu(dd*sum + dd^2*self + bias)
// MODE 2: atomicAdd relu(...) into fp32 out[batch[d]]
template <int C, int MODE>
__global__ __launch_bounds__(256) void node_agg_kernel(
    const ushort_t* __restrict__ h, const int* __restrict__ rowptr,
    const uint_t* __restrict__ epack, const float* __restrict__ dinv,
    const float* __restrict__ bias, const int* __restrict__ batch,
    void* __restrict__ out_v, int n) {
    static_assert(C == 128 || C == 256, "C");
    constexpr int NPG    = (C == 256) ? 4 : 8;   // nodes per wave
    constexpr int GL     = 64 / NPG;             // lanes per group (16 or 8)
    constexpr int LOG_GL = (C == 256) ? 4 : 3;
    constexpr int RS     = C / 2;                // dwords per row
    constexpr int SCH    = 2 * GL;               // channels per slice (32 or 16)

    int slice = blockIdx.x;                      // 0..7 -> XCD
    int tid  = threadIdx.x;
    int wave = tid >> 6, lane = tid & 63;
    int g  = lane >> LOG_GL;
    int cl = lane & (GL - 1);
    int d  = (blockIdx.y * 4 + wave) * NPG + g;
    bool valid = d < n;
    int ds = valid ? d : 0;

    int beg = rowptr[ds];
    int end = rowptr[ds + 1];
    int deg = valid ? (end - beg) : 0;

    // wave-max degree (values uniform within each GL-lane group)
    int m = deg;
    #pragma unroll
    for (int off = GL; off < 64; off <<= 1) {
        int t = __shfl_xor(m, off, 64);
        m = max(m, t);
    }

    const uint_t* hu = (const uint_t*)h;         // dword view of bf16 rows
    int coff = slice * GL + cl;                  // dword offset within row

    float a0 = 0.0f, a1 = 0.0f;
    for (int e = 0; e < m; e += 8) {
        uint_t eps[8];
        #pragma unroll
        for (int u = 0; u < 8; u++) {
            int idx = beg + e + u;
            eps[u] = epack[min(idx, NE - 1)];
        }
        int srcs[8];
        float ws[8];
        #pragma unroll
        for (int u = 0; u < 8; u++) {
            bool act = (e + u) < deg;            // uniform within the group
            srcs[u] = act ? (int)(eps[u] & 0xffffu) : ds;   // self row: L1-hot
            ws[u]   = act ? h16tof(eps[u] >> 16) : 0.0f;
        }
        uint_t rv[8];
        #pragma unroll
        for (int u = 0; u < 8; u++)
            rv[u] = hu[srcs[u] * RS + coff];
        #pragma unroll
        for (int u = 0; u < 8; u++) {
            float w = ws[u];
            a0 += w * __uint_as_float(rv[u] << 16);
            a1 += w * __uint_as_float(rv[u] & 0xffff0000u);
        }
    }

    float dd = dinv[ds];
    uint_t sv = hu[ds * RS + coff];
    float s0 = __uint_as_float(sv << 16);
    float s1 = __uint_as_float(sv & 0xffff0000u);

    float r0, r1;
    if constexpr (MODE >= 1) {
        float2 b2 = *(const float2*)(bias + slice * SCH + 2 * cl);
        r0 = fmaxf(dd * a0 + dd * dd * s0 + b2.x, 0.0f);
        r1 = fmaxf(dd * a1 + dd * dd * s1 + b2.y, 0.0f);
    } else {
        r0 = dd * a0 + dd * dd * s0;
        r1 = dd * a1 + dd * dd * s1;
    }

    if constexpr (MODE == 2) {
        if (valid) {
            float* o = (float*)out_v + (size_t)batch[ds] * C + slice * SCH + 2 * cl;
            atomicAdd(o, r0);
            atomicAdd(o + 1, r1);
        }
    } else {
        if (valid) {
            uint_t* o = (uint_t*)out_v;
            o[d * RS + coff] = (uint_t)f2bf(r0) | ((uint_t)f2bf(r1) << 16);
        }
    }
}

// ================= bf16 MFMA GEMM: C[M,256] = A[M,K] @ Wt[N,K]^T =================
typedef __attribute__((ext_vector_type(8))) short bf16x8;
typedef __attribute__((ext_vector_type(4))) float f32x4;

template <int MODE>
__global__ __launch_bounds__(256) void gemm_bf16_kernel(
    const ushort_t* __restrict__ A, const ushort_t* __restrict__ Wt,
    const float* __restrict__ bias, ushort_t* __restrict__ C, int M, int K) {
    __shared__ ushort_t As[128][40];
    __shared__ ushort_t Bs[128][40];
    int tid = threadIdx.x;
    int row0 = blockIdx.x * 128, col0 = blockIdx.y * 128;
    int lr = tid >> 2, lq = tid & 3;
    int lane = tid & 63, wv = tid >> 6;
    int wr = (wv >> 1) * 64, wc = (wv & 1) * 64;
    int r16 = lane & 15, quad = lane >> 4;

    f32x4 acc[4][4] = {};

    for (int k0 = 0; k0 < K; k0 += 32) {
        {
            int gr0 = row0 + lr, gr1 = row0 + lr + 64;
            uint4 a0 = make_uint4(0, 0, 0, 0), a1 = make_uint4(0, 0, 0, 0);
            if (gr0 < M) a0 = *(const uint4*)(A + (size_t)gr0 * K + k0 + lq * 8);
            if (gr1 < M) a1 = *(const uint4*)(A + (size_t)gr1 * K + k0 + lq * 8);
            *(uint4*)&As[lr][lq * 8]      = a0;
            *(uint4*)&As[lr + 64][lq * 8] = a1;
            uint4 b0 = *(const uint4*)(Wt + (size_t)(col0 + lr) * K + k0 + lq * 8);
            uint4 b1 = *(const uint4*)(Wt + (size_t)(col0 + lr + 64) * K + k0 + lq * 8);
            *(uint4*)&Bs[lr][lq * 8]      = b0;
            *(uint4*)&Bs[lr + 64][lq * 8] = b1;
        }
        __syncthreads();
        bf16x8 af[4], bfr[4];
        #pragma unroll
        for (int i = 0; i < 4; i++) af[i]  = *(const bf16x8*)&As[wr + i * 16 + r16][quad * 8];
        #pragma unroll
        for (int j = 0; j < 4; j++) bfr[j] = *(const bf16x8*)&Bs[wc + j * 16 + r16][quad * 8];
        #pragma unroll
        for (int i = 0; i < 4; i++)
            #pragma unroll
            for (int j = 0; j < 4; j++)
                acc[i][j] = __builtin_amdgcn_mfma_f32_16x16x32_bf16(af[i], bfr[j], acc[i][j], 0, 0, 0);
        __syncthreads();
    }

    #pragma unroll
    for (int j = 0; j < 4; j++) {
        int colc = col0 + wc + j * 16 + r16;
        float bval = (MODE == 1) ? bias[colc] : 0.0f;
        #pragma unroll
        for (int i = 0; i < 4; i++) {
            #pragma unroll
            for (int r = 0; r < 4; r++) {
                int row = row0 + wr + i * 16 + quad * 4 + r;
                if (row < M) {
                    float v = acc[i][j][r];
                    if (MODE == 1) v = fmaxf(v + bval, 0.0f);
                    C[(size_t)row * 256 + colc] = f2bf(v);
                }
            }
        }
    }
}

extern "C" void kernel_launch(void* const* d_in, const int* in_sizes, int n_in,
                              void* d_out, int out_size, void* d_ws, size_t ws_size,
                              hipStream_t stream) {
    const float* x   = (const float*)d_in[0];
    const float* W0  = (const float*)d_in[1];
    const float* b0  = (const float*)d_in[2];
    const float* W1  = (const float*)d_in[3];
    const float* b1  = (const float*)d_in[4];
    const float* W2  = (const float*)d_in[5];
    const float* b2  = (const float*)d_in[6];
    const int*   ei  = (const int*)d_in[7];
    const int*   src = ei;
    const int*   dst = ei + NE;
    const int*   batch = (const int*)d_in[8];
    float* out = (float*)d_out;

    char* ws = (char*)d_ws;
    ushort_t* Abf = (ushort_t*)ws;                        // [NN,256] bf16  25.6 MB
    ushort_t* Bbf = (ushort_t*)(ws + 25600000ull);        // [NN,256] bf16  25.6 MB
    ushort_t* xbf = (ushort_t*)(ws + 51200000ull);        // [NN,128] bf16  12.8 MB
    ushort_t* W0t = (ushort_t*)(ws + 64000000ull);        // [256,128] bf16
    ushort_t* W1t = (ushort_t*)(ws + 64065536ull);        // [256,256] bf16
    ushort_t* W2t = (ushort_t*)(ws + 64196608ull);        // [256,256] bf16
    float*    dinv   = (float*)(ws + 64327680ull);        // [NN]
    int*      rowptr = (int*)  (ws + 64527680ull);        // [NN+1]
    int*      cnt    = (int*)  (ws + 64727808ull);        // [NN]
    uint_t*   epack  = (uint_t*)(ws + 64927808ull);       // [NE] {src:16,f16 dinv:16} 3.2 MB
    int*      bsum   = (int*)  (ws + 71327808ull);        // [<=256]

    const int scanBlocks = (NN + 255) / 256;              // 196
    const dim3 ggrid((NN + 127) / 128, 2);
    // agg grids: x = channel slice (-> XCD), y = node groups
    const dim3 agrid256(8, (NN + 15) / 16);               // 16 nodes/block (4 waves x 4)
    const dim3 agrid128(8, (NN + 31) / 32);               // 32 nodes/block (4 waves x 8)

    // --- prep converts ---
    conv_x_kernel<<<(NN * CIN / 4 + 255) / 256, 256, 0, stream>>>((const float4*)x, (ushort4*)xbf, NN * CIN / 4);
    conv_wt_kernel<<<(CIN * CH + 255) / 256, 256, 0, stream>>>(W0, W0t, CIN, CH);
    conv_wt_kernel<<<(CH * CH + 255) / 256, 256, 0, stream>>>(W1, W1t, CH, CH);
    conv_wt_kernel<<<(CH * CH + 255) / 256, 256, 0, stream>>>(W2, W2t, CH, CH);

    // --- CSR + normalization ---
    hipMemsetAsync(cnt, 0, (size_t)NN * 4, stream);
    count_kernel<<<(NE + 255) / 256, 256, 0, stream>>>(dst, cnt, NE);
    scan_bsum_kernel<<<scanBlocks, 256, 0, stream>>>(cnt, bsum, NN);
    scan_boff_kernel<<<1, 256, 0, stream>>>(bsum, scanBlocks);
    scan_final_kernel<<<scanBlocks, 256, 0, stream>>>(cnt, bsum, rowptr, dinv, NN);
    hipMemsetAsync(cnt, 0, (size_t)NN * 4, stream);       // reuse as cursor
    scatter_kernel<<<(NE + 255) / 256, 256, 0, stream>>>(src, dst, rowptr, cnt, dinv, epack, NE);

    // --- layer 0: aggregate x (128 ch), GEMM0 fused bias+relu ---
    node_agg_kernel<CIN, 0><<<agrid128, 256, 0, stream>>>(xbf, rowptr, epack, dinv, nullptr, nullptr, Bbf, NN);
    gemm_bf16_kernel<1><<<ggrid, 256, 0, stream>>>(Bbf, W0t, b0, Abf, NN, CIN);

    // --- layer 1: GEMM1 plain, aggregate fused bias+relu ---
    gemm_bf16_kernel<0><<<ggrid, 256, 0, stream>>>(Abf, W1t, nullptr, Bbf, NN, CH);
    node_agg_kernel<CH, 1><<<agrid256, 256, 0, stream>>>(Bbf, rowptr, epack, dinv, b1, nullptr, Abf, NN);

    // --- layer 2: GEMM2 plain, aggregate fused bias+relu+pool ---
    gemm_bf16_kernel<0><<<ggrid, 256, 0, stream>>>(Abf, W2t, nullptr, Bbf, NN, CH);
    hipMemsetAsync(out, 0, (size_t)NG * CH * 4, stream);
    node_agg_kernel<CH, 2><<<agrid256, 256, 0, stream>>>(Bbf, rowptr, epack, dinv, b2, batch, out, NN);
}

// Round 2
// 442.126 us; speedup vs baseline: 1.5143x; 1.5143x over previous
//
#include <hip/hip_runtime.h>
#include <hip/hip_fp16.h>

constexpr int NN  = 50000;   // nodes
constexpr int NE  = 800000;  // edges
constexpr int CIN = 128;     // input channels
constexpr int CH  = 256;     // hidden channels
constexpr int NG  = 512;     // graphs

typedef unsigned short ushort_t;
typedef unsigned int uint_t;

static __device__ __forceinline__ ushort_t f2bf(float f) {
    uint_t u = __float_as_uint(f);
    u += 0x7fffu + ((u >> 16) & 1u);   // round-to-nearest-even
    return (ushort_t)(u >> 16);
}

static __device__ __forceinline__ float h16tof(uint_t bits) {
    return __half2float(__ushort_as_half((unsigned short)bits));
}

// ================= prep: fp32 -> bf16 converts =================
__global__ void conv_x_kernel(const float4* __restrict__ x, ushort4* __restrict__ xb, int n4) {
    int i = blockIdx.x * blockDim.x + threadIdx.x;
    if (i >= n4) return;
    float4 v = x[i];
    ushort4 o;
    o.x = f2bf(v.x); o.y = f2bf(v.y); o.z = f2bf(v.z); o.w = f2bf(v.w);
    xb[i] = o;
}

// Wt[n*K + k] = bf16(W[k*N + n])
__global__ void conv_wt_kernel(const float* __restrict__ W, ushort_t* __restrict__ Wt, int K, int N) {
    int i = blockIdx.x * blockDim.x + threadIdx.x;
    if (i >= K * N) return;
    int k = i / N, n = i % N;
    Wt[(size_t)n * K + k] = f2bf(W[i]);
}

// ================= CSR build (8-aligned padded rows) =================
__global__ void count_kernel(const int* __restrict__ dst, int* __restrict__ cnt, int E) {
    int e = blockIdx.x * blockDim.x + threadIdx.x;
    if (e < E) atomicAdd(&cnt[dst[e]], 1);
}

__global__ __launch_bounds__(256) void scan_bsum_kernel(const int* __restrict__ cnt,
                                                        int* __restrict__ bsum, int n) {
    int i = blockIdx.x * 256 + threadIdx.x;
    int v = (i < n) ? ((cnt[i] + 7) & ~7) : 0;   // padded slot count
    #pragma unroll
    for (int off = 32; off >= 1; off >>= 1) v += __shfl_xor(v, off, 64);
    __shared__ int ws[4];
    if ((threadIdx.x & 63) == 0) ws[threadIdx.x >> 6] = v;
    __syncthreads();
    if (threadIdx.x == 0) bsum[blockIdx.x] = ws[0] + ws[1] + ws[2] + ws[3];
}

__global__ __launch_bounds__(256) void scan_boff_kernel(int* __restrict__ bsum, int nb) {
    int tid = threadIdx.x, lane = tid & 63, wid = tid >> 6;
    int v = (tid < nb) ? bsum[tid] : 0;
    int s = v;
    #pragma unroll
    for (int off = 1; off < 64; off <<= 1) {
        int t = __shfl_up(s, off, 64);
        if (lane >= off) s += t;
    }
    __shared__ int wsum[4];
    if (lane == 63) wsum[wid] = s;
    __syncthreads();
    int wadd = 0;
    #pragma unroll
    for (int w = 0; w < 4; w++) if (w < wid) wadd += wsum[w];
    if (tid < nb) bsum[tid] = wadd + s - v;   // exclusive
}

__global__ __launch_bounds__(256) void scan_final_kernel(const int* __restrict__ cnt,
                                                         const int* __restrict__ boff,
                                                         int* __restrict__ rowptr,
                                                         float* __restrict__ dinv, int n) {
    int tid = threadIdx.x, lane = tid & 63, wid = tid >> 6;
    int i = blockIdx.x * 256 + tid;
    int c = (i < n) ? cnt[i] : 0;
    int v = (c + 7) & ~7;                         // padded
    int s = v;
    #pragma unroll
    for (int off = 1; off < 64; off <<= 1) {
        int t = __shfl_up(s, off, 64);
        if (lane >= off) s += t;
    }
    __shared__ int wsum[4];
    if (lane == 63) wsum[wid] = s;
    __syncthreads();
    int wadd = boff[blockIdx.x];
    #pragma unroll
    for (int w = 0; w < 4; w++) if (w < wid) wadd += wsum[w];
    if (i < n) {
        rowptr[i] = wadd + s - v;
        dinv[i]   = rsqrtf((float)c + 1.0f);   // +1 self loop (real degree)
        if (i == n - 1) rowptr[n] = wadd + s;
    }
}

// scatter: write packed {src:16, f16(dinv[src]):16} per padded-CSR slot (4 B/edge).
__global__ void scatter_kernel(const int* __restrict__ src, const int* __restrict__ dst,
                               const int* __restrict__ rowptr, int* __restrict__ cursor,
                               const float* __restrict__ dinv, uint_t* __restrict__ epack, int E) {
    int e = blockIdx.x * blockDim.x + threadIdx.x;
    if (e >= E) return;
    int d = dst[e];
    int s = src[e];
    int p = rowptr[d] + atomicAdd(&cursor[d], 1);
    uint_t hb = (uint_t)__half_as_ushort(__float2half(dinv[s]));
    epack[p] = (uint_t)s | (hb << 16);
}

// ================= per-node gather aggregation (bf16) ====
// One wave per node (proven best unit: wave-uniform full-row gathers).
// Rate optimizations vs round-0:
//  - 8-aligned CSR blocks -> epack block = two uint4 loads (not 8 clamped dwords)
//  - software-pipelined epack prefetch (next block issued before current FMAs)
//  - readfirstlane src -> SGPR-base gathers, kills per-lane 64-bit addr math
// MODE 0: out(bf16) = dd*sum + dd^2*self
// MODE 1: out(bf16) = relu(dd*sum + dd^2*self + bias)
// MODE 2: atomicAdd relu(...) into fp32 out[batch[d]]
template <int C, int MODE>
__global__ __launch_bounds__(256) void node_agg_kernel(
    const ushort_t* __restrict__ h, const int* __restrict__ rowptr,
    const int* __restrict__ degc, const uint_t* __restrict__ epack,
    const float* __restrict__ dinv, const float* __restrict__ bias,
    const int* __restrict__ batch, void* __restrict__ out_v, int n) {
    constexpr int V = C / 64;                 // dwords (2 bf16) per lane per row
    int wave = threadIdx.x >> 6;
    int lane = threadIdx.x & 63;
    int d = blockIdx.x * 4 + wave;
    if (d >= n) return;

    int beg = __builtin_amdgcn_readfirstlane(rowptr[d]);
    int deg = __builtin_amdgcn_readfirstlane(degc[d]);
    const uint_t* hu = (const uint_t*)h;

    float acc[V] = {};
    const uint4* ep4 = (const uint4*)(epack + beg);   // 32 B aligned (beg % 8 == 0)
    uint4 ea, eb, na, nb;
    if (deg > 0) { ea = ep4[0]; eb = ep4[1]; }

    for (int e = 0; e < deg; e += 8) {
        int blk = e >> 3;
        if (e + 8 < deg) { na = ep4[blk * 2 + 2]; nb = ep4[blk * 2 + 3]; }
        uint_t eps[8] = {ea.x, ea.y, ea.z, ea.w, eb.x, eb.y, eb.z, eb.w};
        int   srcs[8];
        float wts[8];
        #pragma unroll
        for (int u = 0; u < 8; u++) {
            bool a = (e + u) < deg;           // wave-uniform
            srcs[u] = a ? (int)(eps[u] & 0xffffu) : d;
            wts[u]  = a ? h16tof(eps[u] >> 16) : 0.0f;
        }
        if constexpr (V == 4) {
            uint_t ra[8], rb[8];
            #pragma unroll
            for (int u = 0; u < 8; u++) {
                const uint_t* row = hu + (size_t)__builtin_amdgcn_readfirstlane(srcs[u]) * (C / 2);
                ra[u] = row[lane];            // channels 2l,2l+1 (bytes 0..255)
                rb[u] = row[64 + lane];       // channels 128+2l,128+2l+1
            }
            #pragma unroll
            for (int u = 0; u < 8; u++) {
                float w = wts[u];
                acc[0] += w * __uint_as_float(ra[u] << 16);
                acc[1] += w * __uint_as_float(ra[u] & 0xffff0000u);
                acc[2] += w * __uint_as_float(rb[u] << 16);
                acc[3] += w * __uint_as_float(rb[u] & 0xffff0000u);
            }
        } else {
            uint_t rv[8];
            #pragma unroll
            for (int u = 0; u < 8; u++) {
                const uint_t* row = hu + (size_t)__builtin_amdgcn_readfirstlane(srcs[u]) * (C / 2);
                rv[u] = row[lane];
            }
            #pragma unroll
            for (int u = 0; u < 8; u++) {
                float w = wts[u];
                acc[0] += w * __uint_as_float(rv[u] << 16);
                acc[1] += w * __uint_as_float(rv[u] & 0xffff0000u);
            }
        }
        ea = na; eb = nb;
    }

    float dd = dinv[d];
    float self[V];
    {
        const uint_t* row = hu + (size_t)d * (C / 2);
        uint_t sa = row[lane];
        self[0] = __uint_as_float(sa << 16);
        self[1] = __uint_as_float(sa & 0xffff0000u);
        if constexpr (V == 4) {
            uint_t sb = row[64 + lane];
            self[2] = __uint_as_float(sb << 16);
            self[3] = __uint_as_float(sb & 0xffff0000u);
        }
    }

    float r[V];
    if constexpr (MODE >= 1) {
        float2 bA = *(const float2*)(bias + 2 * lane);
        r[0] = fmaxf(dd * acc[0] + dd * dd * self[0] + bA.x, 0.0f);
        r[1] = fmaxf(dd * acc[1] + dd * dd * self[1] + bA.y, 0.0f);
        if constexpr (V == 4) {
            float2 bB = *(const float2*)(bias + 128 + 2 * lane);
            r[2] = fmaxf(dd * acc[2] + dd * dd * self[2] + bB.x, 0.0f);
            r[3] = fmaxf(dd * acc[3] + dd * dd * self[3] + bB.y, 0.0f);
        }
    } else {
        #pragma unroll
        for (int i = 0; i < V; i++)
            r[i] = dd * acc[i] + dd * dd * self[i];
    }

    if constexpr (MODE == 2) {
        float* o = (float*)out_v + (size_t)batch[d] * C;
        atomicAdd(o + 2 * lane, r[0]);
        atomicAdd(o + 2 * lane + 1, r[1]);
        if constexpr (V == 4) {
            atomicAdd(o + 128 + 2 * lane, r[2]);
            atomicAdd(o + 128 + 2 * lane + 1, r[3]);
        }
    } else {
        uint_t* o = (uint_t*)((ushort_t*)out_v + (size_t)d * C);
        o[lane] = (uint_t)f2bf(r[0]) | ((uint_t)f2bf(r[1]) << 16);
        if constexpr (V == 4)
            o[64 + lane] = (uint_t)f2bf(r[2]) | ((uint_t)f2bf(r[3]) << 16);
    }
}

// ================= bf16 MFMA GEMM: C[M,256] = A[M,K] @ Wt[N,K]^T =================
typedef __attribute__((ext_vector_type(8))) short bf16x8;
typedef __attribute__((ext_vector_type(4))) float f32x4;

template <int MODE>
__global__ __launch_bounds__(256) void gemm_bf16_kernel(
    const ushort_t* __restrict__ A, const ushort_t* __restrict__ Wt,
    const float* __restrict__ bias, ushort_t* __restrict__ C, int M, int K) {
    __shared__ ushort_t As[128][40];
    __shared__ ushort_t Bs[128][40];
    int tid = threadIdx.x;
    int row0 = blockIdx.x * 128, col0 = blockIdx.y * 128;
    int lr = tid >> 2, lq = tid & 3;
    int lane = tid & 63, wv = tid >> 6;
    int wr = (wv >> 1) * 64, wc = (wv & 1) * 64;
    int r16 = lane & 15, quad = lane >> 4;

    f32x4 acc[4][4] = {};

    for (int k0 = 0; k0 < K; k0 += 32) {
        {
            int gr0 = row0 + lr, gr1 = row0 + lr + 64;
            uint4 a0 = make_uint4(0, 0, 0, 0), a1 = make_uint4(0, 0, 0, 0);
            if (gr0 < M) a0 = *(const uint4*)(A + (size_t)gr0 * K + k0 + lq * 8);
            if (gr1 < M) a1 = *(const uint4*)(A + (size_t)gr1 * K + k0 + lq * 8);
            *(uint4*)&As[lr][lq * 8]      = a0;
            *(uint4*)&As[lr + 64][lq * 8] = a1;
            uint4 b0 = *(const uint4*)(Wt + (size_t)(col0 + lr) * K + k0 + lq * 8);
            uint4 b1 = *(const uint4*)(Wt + (size_t)(col0 + lr + 64) * K + k0 + lq * 8);
            *(uint4*)&Bs[lr][lq * 8]      = b0;
            *(uint4*)&Bs[lr + 64][lq * 8] = b1;
        }
        __syncthreads();
        bf16x8 af[4], bfr[4];
        #pragma unroll
        for (int i = 0; i < 4; i++) af[i]  = *(const bf16x8*)&As[wr + i * 16 + r16][quad * 8];
        #pragma unroll
        for (int j = 0; j < 4; j++) bfr[j] = *(const bf16x8*)&Bs[wc + j * 16 + r16][quad * 8];
        #pragma unroll
        for (int i = 0; i < 4; i++)
            #pragma unroll
            for (int j = 0; j < 4; j++)
                acc[i][j] = __builtin_amdgcn_mfma_f32_16x16x32_bf16(af[i], bfr[j], acc[i][j], 0, 0, 0);
        __syncthreads();
    }

    #pragma unroll
    for (int j = 0; j < 4; j++) {
        int colc = col0 + wc + j * 16 + r16;
        float bval = (MODE == 1) ? bias[colc] : 0.0f;
        #pragma unroll
        for (int i = 0; i < 4; i++) {
            #pragma unroll
            for (int r = 0; r < 4; r++) {
                int row = row0 + wr + i * 16 + quad * 4 + r;
                if (row < M) {
                    float v = acc[i][j][r];
                    if (MODE == 1) v = fmaxf(v + bval, 0.0f);
                    C[(size_t)row * 256 + colc] = f2bf(v);
                }
            }
        }
    }
}

extern "C" void kernel_launch(void* const* d_in, const int* in_sizes, int n_in,
                              void* d_out, int out_size, void* d_ws, size_t ws_size,
                              hipStream_t stream) {
    const float* x   = (const float*)d_in[0];
    const float* W0  = (const float*)d_in[1];
    const float* b0  = (const float*)d_in[2];
    const float* W1  = (const float*)d_in[3];
    const float* b1  = (const float*)d_in[4];
    const float* W2  = (const float*)d_in[5];
    const float* b2  = (const float*)d_in[6];
    const int*   ei  = (const int*)d_in[7];
    const int*   src = ei;
    const int*   dst = ei + NE;
    const int*   batch = (const int*)d_in[8];
    float* out = (float*)d_out;

    char* ws = (char*)d_ws;
    ushort_t* Abf = (ushort_t*)ws;                        // [NN,256] bf16  25.6 MB
    ushort_t* Bbf = (ushort_t*)(ws + 25600000ull);        // [NN,256] bf16  25.6 MB
    ushort_t* xbf = (ushort_t*)(ws + 51200000ull);        // [NN,128] bf16  12.8 MB
    ushort_t* W0t = (ushort_t*)(ws + 64000000ull);        // [256,128] bf16
    ushort_t* W1t = (ushort_t*)(ws + 64065536ull);        // [256,256] bf16
    ushort_t* W2t = (ushort_t*)(ws + 64196608ull);        // [256,256] bf16
    float*    dinv   = (float*)(ws + 64327680ull);        // [NN]
    int*      rowptr = (int*)  (ws + 64527680ull);        // [NN+1]
    int*      cnt    = (int*)  (ws + 64727808ull);        // [NN] real degrees (kept)
    uint_t*   epack  = (uint_t*)(ws + 64927808ull);       // [<=NE+8*NN] padded, 4.8 MB max
    int*      bsum   = (int*)  (ws + 71327808ull);        // [<=256]
    int*      cursor = (int*)ws;                          // aliases Abf (free until GEMM0)

    const int scanBlocks = (NN + 255) / 256;              // 196
    const int nodeBlocks = (NN + 3) / 4;                  // 1 node per wave, 4 waves/block
    const dim3 ggrid((NN + 127) / 128, 2);

    // --- prep converts ---
    conv_x_kernel<<<(NN * CIN / 4 + 255) / 256, 256, 0, stream>>>((const float4*)x, (ushort4*)xbf, NN * CIN / 4);
    conv_wt_kernel<<<(CIN * CH + 255) / 256, 256, 0, stream>>>(W0, W0t, CIN, CH);
    conv_wt_kernel<<<(CH * CH + 255) / 256, 256, 0, stream>>>(W1, W1t, CH, CH);
    conv_wt_kernel<<<(CH * CH + 255) / 256, 256, 0, stream>>>(W2, W2t, CH, CH);

    // --- CSR + normalization (8-aligned padded rows) ---
    hipMemsetAsync(cnt, 0, (size_t)NN * 4, stream);
    count_kernel<<<(NE + 255) / 256, 256, 0, stream>>>(dst, cnt, NE);
    scan_bsum_kernel<<<scanBlocks, 256, 0, stream>>>(cnt, bsum, NN);
    scan_boff_kernel<<<1, 256, 0, stream>>>(bsum, scanBlocks);
    scan_final_kernel<<<scanBlocks, 256, 0, stream>>>(cnt, bsum, rowptr, dinv, NN);
    hipMemsetAsync(cursor, 0, (size_t)NN * 4, stream);
    scatter_kernel<<<(NE + 255) / 256, 256, 0, stream>>>(src, dst, rowptr, cursor, dinv, epack, NE);

    // --- layer 0: aggregate x (128 ch), GEMM0 fused bias+relu ---
    node_agg_kernel<CIN, 0><<<nodeBlocks, 256, 0, stream>>>(xbf, rowptr, cnt, epack, dinv, nullptr, nullptr, Bbf, NN);
    gemm_bf16_kernel<1><<<ggrid, 256, 0, stream>>>(Bbf, W0t, b0, Abf, NN, CIN);

    // --- layer 1: GEMM1 plain, aggregate fused bias+relu ---
    gemm_bf16_kernel<0><<<ggrid, 256, 0, stream>>>(Abf, W1t, nullptr, Bbf, NN, CH);
    node_agg_kernel<CH, 1><<<nodeBlocks, 256, 0, stream>>>(Bbf, rowptr, cnt, epack, dinv, b1, nullptr, Abf, NN);

    // --- layer 2: GEMM2 plain, aggregate fused bias+relu+pool ---
    gemm_bf16_kernel<0><<<ggrid, 256, 0, stream>>>(Abf, W2t, nullptr, Bbf, NN, CH);
    hipMemsetAsync(out, 0, (size_t)NG * CH * 4, stream);
    node_agg_kernel<CH, 2><<<nodeBlocks, 256, 0, stream>>>(Bbf, rowptr, cnt, epack, dinv, b2, batch, out, NN);
}